// Round 1
// baseline (936.991 us; speedup 1.0000x reference)
//
#include <hip/hip_runtime.h>

#define C 128

typedef __bf16 bf16_t;
typedef bf16_t bf16x8 __attribute__((ext_vector_type(8)));
typedef float f32x4 __attribute__((ext_vector_type(4)));

// ---- degree: deg[row[e]] += 1 ----
__global__ void deg_kernel(const int* __restrict__ row, float* __restrict__ deg, int e) {
    int i = blockIdx.x * blockDim.x + threadIdx.x;
    if (i < e) atomicAdd(&deg[row[i]], 1.0f);
}

// ---- dis = deg>0 ? rsqrt(deg) : 0  (in place) ----
__global__ void dis_kernel(float* __restrict__ deg, int n) {
    int i = blockIdx.x * blockDim.x + threadIdx.x;
    if (i < n) {
        float d = deg[i];
        deg[i] = d > 0.f ? rsqrtf(d) : 0.f;
    }
}

// ---- norm[i] = dis[row[i]] * dis[col[i]] ----
__global__ void norm_kernel(const int* __restrict__ row, const int* __restrict__ col,
                            const float* __restrict__ dis, float* __restrict__ nrm, int e) {
    int i = blockIdx.x * blockDim.x + threadIdx.x;
    if (i < e) nrm[i] = dis[row[i]] * dis[col[i]];
}

// ---- scatter: out[row[e]][c] += norm[col[e]] * x[col[e]][c]; cnt[row[e]] += norm[col[e]] ----
__global__ void scatter_kernel(const int* __restrict__ row, const int* __restrict__ col,
                               const float* __restrict__ nrm, const float* __restrict__ x,
                               float* __restrict__ out, float* __restrict__ cnt, int e) {
    long gid = (long)blockIdx.x * blockDim.x + threadIdx.x;
    int edge = (int)(gid >> 7);
    int ch   = (int)(gid & 127);
    if (edge >= e) return;
    int r = row[edge];
    int c = col[edge];
    float w = nrm[c];
    atomicAdd(&out[(long)r * C + ch], w * x[(long)c * C + ch]);
    if (ch == 0) atomicAdd(&cnt[r], w);
}

// ---- in-place linear: out[r] = Z[r] @ W^T + cnt[r] * b ----
// One wave owns 16 rows. A-frag: lane holds Z[r0 + (lane&15)][kc*32 + (lane>>4)*8 + j]
// B-frag: lane holds W[t*16 + (lane&15)][kc*32 + (lane>>4)*8 + j]   (B[k][n] = W[n][k])
// C: col = lane&15, row = (lane>>4)*4 + reg
__global__ __launch_bounds__(256) void gemm_kernel(
        float* __restrict__ out, const float* __restrict__ W,
        const float* __restrict__ b, const float* __restrict__ cnt, int n)
{
    const int lane = threadIdx.x & 63;
    const int wave = threadIdx.x >> 6;
    const int m    = lane & 15;
    const int quad = lane >> 4;
    const long r0  = ((long)blockIdx.x * 4 + wave) * 16;
    if (r0 >= n) return;

    // load A fragments (all 16 rows' K=128 read BEFORE any store -> in-place safe)
    bf16x8 a[4];
    const float* zrow = out + (r0 + m) * C;
    #pragma unroll
    for (int kc = 0; kc < 4; ++kc) {
        const float* p = zrow + kc * 32 + quad * 8;
        #pragma unroll
        for (int j = 0; j < 8; ++j) a[kc][j] = (bf16_t)p[j];
    }

    float cv[4];
    #pragma unroll
    for (int v = 0; v < 4; ++v) cv[v] = cnt[r0 + quad * 4 + v];

    for (int t = 0; t < 8; ++t) {
        const int o = t * 16 + m;
        const float* wrow = W + o * C;
        bf16x8 bf[4];
        #pragma unroll
        for (int kc = 0; kc < 4; ++kc) {
            const float* p = wrow + kc * 32 + quad * 8;
            #pragma unroll
            for (int j = 0; j < 8; ++j) bf[kc][j] = (bf16_t)p[j];
        }
        f32x4 c = {0.f, 0.f, 0.f, 0.f};
        #pragma unroll
        for (int kc = 0; kc < 4; ++kc)
            c = __builtin_amdgcn_mfma_f32_16x16x32_bf16(a[kc], bf[kc], c, 0, 0, 0);
        const float bias = b[o];
        #pragma unroll
        for (int v = 0; v < 4; ++v) {
            const long r = r0 + quad * 4 + v;
            out[r * C + o] = c[v] + cv[v] * bias;
        }
    }
}

extern "C" void kernel_launch(void* const* d_in, const int* in_sizes, int n_in,
                              void* d_out, int out_size, void* d_ws, size_t ws_size,
                              hipStream_t stream) {
    const float* x  = (const float*)d_in[0];
    const int*   ei = (const int*)d_in[1];
    const float* W  = (const float*)d_in[2];
    const float* b  = (const float*)d_in[3];
    float* out = (float*)d_out;

    const int n = in_sizes[0] / C;   // nodes
    const int e = in_sizes[1] / 2;   // edges (== n)
    const int* row = ei;
    const int* col = ei + e;

    float* deg = (float*)d_ws;   // [n]  (becomes dis in-place)
    float* cnt = deg + n;        // [n]
    float* nrm = cnt + n;        // [e]

    hipMemsetAsync(deg, 0, (size_t)2 * n * sizeof(float), stream);           // deg + cnt
    hipMemsetAsync(out, 0, (size_t)n * C * sizeof(float), stream);

    deg_kernel<<<(e + 255) / 256, 256, 0, stream>>>(row, deg, e);
    dis_kernel<<<(n + 255) / 256, 256, 0, stream>>>(deg, n);
    norm_kernel<<<(e + 255) / 256, 256, 0, stream>>>(row, col, deg, nrm, e);

    long tot = (long)e * C;
    scatter_kernel<<<(int)((tot + 255) / 256), 256, 0, stream>>>(row, col, nrm, x, out, cnt, e);

    int groups = (n + 15) / 16;
    int blocks = (groups + 3) / 4;
    gemm_kernel<<<blocks, 256, 0, stream>>>(out, W, b, cnt, n);
}

// Round 2
// 812.571 us; speedup vs baseline: 1.1531x; 1.1531x over previous
//
#include <hip/hip_runtime.h>

#define C 128

typedef __bf16 bf16_t;
typedef bf16_t bf16x8 __attribute__((ext_vector_type(8)));
typedef float f32x4 __attribute__((ext_vector_type(4)));

// ---- degree histogram (int) ----
__global__ void deg_kernel(const int* __restrict__ row, int* __restrict__ deg, int e) {
    int i = blockIdx.x * blockDim.x + threadIdx.x;
    if (i < e) atomicAdd(&deg[row[i]], 1);
}

// ---- dis[i] = deg>0 ? rsqrt(deg) : 0 ----
__global__ void dis_kernel(const int* __restrict__ deg, float* __restrict__ dis, int n) {
    int i = blockIdx.x * blockDim.x + threadIdx.x;
    if (i < n) {
        int d = deg[i];
        dis[i] = d > 0 ? rsqrtf((float)d) : 0.f;
    }
}

// ---- nrm[i] = dis[row[i]] * dis[col[i]] ----
__global__ void norm_kernel(const int* __restrict__ row, const int* __restrict__ col,
                            const float* __restrict__ dis, float* __restrict__ nrm, int e) {
    int i = blockIdx.x * blockDim.x + threadIdx.x;
    if (i < e) nrm[i] = dis[row[i]] * dis[col[i]];
}

// ---- scan stage 1: per-block (1024 items) exclusive scan + block totals ----
__global__ __launch_bounds__(256) void scan1_kernel(const int* __restrict__ deg,
                                                    int* __restrict__ offs,
                                                    int* __restrict__ partials, int n) {
    __shared__ int s[256];
    const int tid = threadIdx.x;
    const int base = blockIdx.x * 1024 + tid * 4;
    int v[4];
    #pragma unroll
    for (int j = 0; j < 4; ++j) v[j] = (base + j < n) ? deg[base + j] : 0;
    int tsum = v[0] + v[1] + v[2] + v[3];
    s[tid] = tsum;
    __syncthreads();
    for (int off = 1; off < 256; off <<= 1) {
        int t = (tid >= off) ? s[tid - off] : 0;
        __syncthreads();
        s[tid] += t;
        __syncthreads();
    }
    int excl = s[tid] - tsum;   // exclusive prefix of this thread's 4 items
    #pragma unroll
    for (int j = 0; j < 4; ++j) {
        if (base + j < n) offs[base + j] = excl;
        excl += v[j];
    }
    if (tid == 255) partials[blockIdx.x] = s[255];
}

// ---- scan stage 2: single block scans the block totals (exclusive, in place) ----
__global__ __launch_bounds__(1024) void scan2_kernel(int* __restrict__ partials, int nb) {
    __shared__ int s[1024];
    const int tid = threadIdx.x;
    int v = (tid < nb) ? partials[tid] : 0;
    s[tid] = v;
    __syncthreads();
    for (int off = 1; off < 1024; off <<= 1) {
        int t = (tid >= off) ? s[tid - off] : 0;
        __syncthreads();
        s[tid] += t;
        __syncthreads();
    }
    if (tid < nb) partials[tid] = s[tid] - v;   // exclusive
}

// ---- scan stage 3: add scanned block totals ----
__global__ __launch_bounds__(256) void scan3_kernel(int* __restrict__ offs,
                                                    const int* __restrict__ partials, int n) {
    const int add = partials[blockIdx.x];
    const int base = blockIdx.x * 1024 + threadIdx.x * 4;
    #pragma unroll
    for (int j = 0; j < 4; ++j)
        if (base + j < n) offs[base + j] += add;
}

// ---- bucket edges into CSR ----
__global__ void bucket_kernel(const int* __restrict__ row, const int* __restrict__ col,
                              const int* __restrict__ offs, int* __restrict__ cursor,
                              int* __restrict__ csr_col, int e) {
    int i = blockIdx.x * blockDim.x + threadIdx.x;
    if (i < e) {
        int r = row[i];
        int pos = atomicAdd(&cursor[r], 1);
        csr_col[offs[r] + pos] = col[i];
    }
}

// ---- gather: out[r] = sum_e nrm[col_e] * x[col_e]; cnt[r] = sum_e nrm[col_e] ----
// 32 threads per row (float4 lanes), 8 rows per 256-block. No atomics.
__global__ __launch_bounds__(256) void gather_kernel(
        const float4* __restrict__ x4, const int* __restrict__ csr_col,
        const int* __restrict__ offs, const int* __restrict__ deg,
        const float* __restrict__ nrm, float4* __restrict__ out4,
        float* __restrict__ cnt, int n)
{
    const int t = threadIdx.x;
    const int ch = t & 31;
    const int r = blockIdx.x * 8 + (t >> 5);
    if (r >= n) return;
    const int start = offs[r];
    const int d = deg[r];
    float4 acc = {0.f, 0.f, 0.f, 0.f};
    float sw = 0.f;
    for (int k = 0; k < d; ++k) {
        int c = csr_col[start + k];
        float w = nrm[c];
        sw += w;
        float4 xv = x4[c * 32 + ch];
        acc.x += w * xv.x; acc.y += w * xv.y; acc.z += w * xv.z; acc.w += w * xv.w;
    }
    out4[(long)r * 32 + ch] = acc;
    if (ch == 0) cnt[r] = sw;
}

// ---- in-place linear: out[r] = Z[r] @ W^T + cnt[r] * b (validated round 1) ----
__global__ __launch_bounds__(256) void gemm_kernel(
        float* __restrict__ out, const float* __restrict__ W,
        const float* __restrict__ b, const float* __restrict__ cnt, int n)
{
    const int lane = threadIdx.x & 63;
    const int wave = threadIdx.x >> 6;
    const int m    = lane & 15;
    const int quad = lane >> 4;
    const long r0  = ((long)blockIdx.x * 4 + wave) * 16;
    if (r0 >= n) return;

    bf16x8 a[4];
    const float* zrow = out + (r0 + m) * C;
    #pragma unroll
    for (int kc = 0; kc < 4; ++kc) {
        const float* p = zrow + kc * 32 + quad * 8;
        #pragma unroll
        for (int j = 0; j < 8; ++j) a[kc][j] = (bf16_t)p[j];
    }

    float cv[4];
    #pragma unroll
    for (int v = 0; v < 4; ++v) cv[v] = cnt[r0 + quad * 4 + v];

    for (int t = 0; t < 8; ++t) {
        const int o = t * 16 + m;
        const float* wrow = W + o * C;
        bf16x8 bf[4];
        #pragma unroll
        for (int kc = 0; kc < 4; ++kc) {
            const float* p = wrow + kc * 32 + quad * 8;
            #pragma unroll
            for (int j = 0; j < 8; ++j) bf[kc][j] = (bf16_t)p[j];
        }
        f32x4 c = {0.f, 0.f, 0.f, 0.f};
        #pragma unroll
        for (int kc = 0; kc < 4; ++kc)
            c = __builtin_amdgcn_mfma_f32_16x16x32_bf16(a[kc], bf[kc], c, 0, 0, 0);
        const float bias = b[o];
        #pragma unroll
        for (int v = 0; v < 4; ++v) {
            const long r = r0 + quad * 4 + v;
            out[r * C + o] = c[v] + cv[v] * bias;
        }
    }
}

extern "C" void kernel_launch(void* const* d_in, const int* in_sizes, int n_in,
                              void* d_out, int out_size, void* d_ws, size_t ws_size,
                              hipStream_t stream) {
    const float* x  = (const float*)d_in[0];
    const int*   ei = (const int*)d_in[1];
    const float* W  = (const float*)d_in[2];
    const float* b  = (const float*)d_in[3];
    float* out = (float*)d_out;

    const int n = in_sizes[0] / C;   // nodes
    const int e = in_sizes[1] / 2;   // edges (== n)
    const int* row = ei;
    const int* col = ei + e;

    int*   deg_i   = (int*)d_ws;          // [n]
    int*   offs    = deg_i + n;           // [n]
    int*   cursor  = offs + n;            // [n]   (aliased as cnt after bucketing)
    int*   csr_col = cursor + n;          // [e]
    float* dis     = (float*)(csr_col + e);  // [n]
    float* nrm     = dis + n;             // [e]
    int*   partials = (int*)(nrm + e);    // [<=1024]
    float* cnt     = (float*)cursor;

    const int nb = (n + 1023) / 1024;    // scan blocks (489 for n=500k, must be <=1024)

    // zero deg + offs + cursor in one shot (offs overwritten by scan anyway)
    hipMemsetAsync(deg_i, 0, (size_t)3 * n * sizeof(int), stream);

    deg_kernel<<<(e + 255) / 256, 256, 0, stream>>>(row, deg_i, e);
    dis_kernel<<<(n + 255) / 256, 256, 0, stream>>>(deg_i, dis, n);
    norm_kernel<<<(e + 255) / 256, 256, 0, stream>>>(row, col, dis, nrm, e);

    scan1_kernel<<<nb, 256, 0, stream>>>(deg_i, offs, partials, n);
    scan2_kernel<<<1, 1024, 0, stream>>>(partials, nb);
    scan3_kernel<<<nb, 256, 0, stream>>>(offs, partials, n);

    bucket_kernel<<<(e + 255) / 256, 256, 0, stream>>>(row, col, offs, cursor, csr_col, e);

    gather_kernel<<<(n + 7) / 8, 256, 0, stream>>>(
        (const float4*)x, csr_col, offs, deg_i, nrm, (float4*)out, cnt, n);

    int groups = (n + 15) / 16;
    int blocks = (groups + 3) / 4;
    gemm_kernel<<<blocks, 256, 0, stream>>>(out, W, b, cnt, n);
}

// Round 4
// 685.579 us; speedup vs baseline: 1.3667x; 1.1852x over previous
//
#include <hip/hip_runtime.h>

#define C 128

typedef __bf16 bf16_t;
typedef bf16_t bf16x8 __attribute__((ext_vector_type(8)));
typedef float f32x4 __attribute__((ext_vector_type(4)));

// ---- degree histogram (int) ----
__global__ void deg_kernel(const int* __restrict__ row, int* __restrict__ deg, int e) {
    int i = blockIdx.x * blockDim.x + threadIdx.x;
    if (i < e) atomicAdd(&deg[row[i]], 1);
}

// ---- scan stage 1: per-block (1024 items) exclusive scan + block totals + dis ----
__global__ __launch_bounds__(256) void scan1_kernel(const int* __restrict__ deg,
                                                    float* __restrict__ dis,
                                                    int* __restrict__ offs,
                                                    int* __restrict__ partials, int n) {
    __shared__ int s[256];
    const int tid = threadIdx.x;
    const int base = blockIdx.x * 1024 + tid * 4;
    int v[4];
    #pragma unroll
    for (int j = 0; j < 4; ++j) v[j] = (base + j < n) ? deg[base + j] : 0;
    #pragma unroll
    for (int j = 0; j < 4; ++j)
        if (base + j < n) dis[base + j] = v[j] > 0 ? rsqrtf((float)v[j]) : 0.f;
    int tsum = v[0] + v[1] + v[2] + v[3];
    s[tid] = tsum;
    __syncthreads();
    for (int off = 1; off < 256; off <<= 1) {
        int t = (tid >= off) ? s[tid - off] : 0;
        __syncthreads();
        s[tid] += t;
        __syncthreads();
    }
    int excl = s[tid] - tsum;
    #pragma unroll
    for (int j = 0; j < 4; ++j) {
        if (base + j < n) offs[base + j] = excl;
        excl += v[j];
    }
    if (tid == 255) partials[blockIdx.x] = s[255];
}

// ---- scan stage 2: single block scans the block totals (exclusive, in place) ----
__global__ __launch_bounds__(1024) void scan2_kernel(int* __restrict__ partials, int nb) {
    __shared__ int s[1024];
    const int tid = threadIdx.x;
    int v = (tid < nb) ? partials[tid] : 0;
    s[tid] = v;
    __syncthreads();
    for (int off = 1; off < 1024; off <<= 1) {
        int t = (tid >= off) ? s[tid - off] : 0;
        __syncthreads();
        s[tid] += t;
        __syncthreads();
    }
    if (tid < nb) partials[tid] = s[tid] - v;
}

// ---- nrm[i] = dis[row[i]] * dis[col[i]]   (i is an EDGE index; the reference
//      then uses nrm[col[e]] as the weight — nested indexing, do NOT factor) ----
__global__ void norm_kernel(const int* __restrict__ row, const int* __restrict__ col,
                            const float* __restrict__ dis, float* __restrict__ nrm, int e) {
    int i = blockIdx.x * blockDim.x + threadIdx.x;
    if (i < e) nrm[i] = dis[row[i]] * dis[col[i]];
}

// ---- bucket edges into CSR; store w = nrm[col[i]] alongside ----
__global__ void bucket_kernel(const int* __restrict__ row, const int* __restrict__ col,
                              const int* __restrict__ offs, const int* __restrict__ partials,
                              const float* __restrict__ nrm, int* __restrict__ cursor,
                              int* __restrict__ csr_col, float* __restrict__ csr_w, int e) {
    int i = blockIdx.x * blockDim.x + threadIdx.x;
    if (i < e) {
        int r = row[i];
        int c = col[i];
        int pos = atomicAdd(&cursor[r], 1);
        int idx = offs[r] + partials[r >> 10] + pos;
        csr_col[idx] = c;
        csr_w[idx] = nrm[c];
    }
}

// ---- fused gather + linear ----
// out[r] = (sum_e w_e * x[c_e]) @ W^T + (sum_e w_e) * b,  w_e = nrm[col[e]].
// Wave owns 16 rows. Lane (m,quad) accumulates Z[r0+m][kc*32+quad*8+j] directly
// in MFMA A-fragment layout (no LDS, no Z round-trip).
__global__ __launch_bounds__(256) void fused_kernel(
        const f32x4* __restrict__ x4, const int* __restrict__ csr_col,
        const float* __restrict__ csr_w, const int* __restrict__ offs,
        const int* __restrict__ partials, const int* __restrict__ deg,
        const f32x4* __restrict__ W4, const float* __restrict__ bias,
        float* __restrict__ out, int n)
{
    const int lane = threadIdx.x & 63;
    const int wave = threadIdx.x >> 6;
    const int m    = lane & 15;
    const int quad = lane >> 4;
    const long r0  = ((long)blockIdx.x * 4 + wave) * 16;
    if (r0 >= n) return;
    const int  r  = (int)r0 + m;
    const bool rv = r < n;
    const int  d     = rv ? deg[r] : 0;
    const int  start = rv ? offs[r] + partials[r >> 10] : 0;

    f32x4 acc[8];
    #pragma unroll
    for (int i = 0; i < 8; ++i) acc[i] = (f32x4){0.f, 0.f, 0.f, 0.f};
    float sw = 0.f;

    for (int k = 0; k < d; ++k) {
        const int   c = csr_col[start + k];
        const float w = csr_w[start + k];
        sw += w;
        const f32x4* xr = x4 + (long)c * 32 + quad * 2;
        #pragma unroll
        for (int kc = 0; kc < 4; ++kc) {
            f32x4 v0 = xr[kc * 8];
            f32x4 v1 = xr[kc * 8 + 1];
            acc[kc * 2]     += w * v0;
            acc[kc * 2 + 1] += w * v1;
        }
    }

    // convert to MFMA A fragments (A[m][k = quad*8+j] per 32-wide K chunk)
    bf16x8 a[4];
    #pragma unroll
    for (int kc = 0; kc < 4; ++kc) {
        #pragma unroll
        for (int j = 0; j < 4; ++j) {
            a[kc][j]     = (bf16_t)acc[kc * 2][j];
            a[kc][j + 4] = (bf16_t)acc[kc * 2 + 1][j];
        }
    }

    // cnt for the 4 output rows this lane stores (C-layout: row = quad*4+v)
    float cv[4];
    #pragma unroll
    for (int v = 0; v < 4; ++v) cv[v] = __shfl(sw, quad * 4 + v);

    for (int t = 0; t < 8; ++t) {
        const int o = t * 16 + m;
        const f32x4* wrow = W4 + (long)o * 32 + quad * 2;
        bf16x8 bf[4];
        #pragma unroll
        for (int kc = 0; kc < 4; ++kc) {
            f32x4 w0 = wrow[kc * 8];
            f32x4 w1 = wrow[kc * 8 + 1];
            #pragma unroll
            for (int j = 0; j < 4; ++j) {
                bf[kc][j]     = (bf16_t)w0[j];
                bf[kc][j + 4] = (bf16_t)w1[j];
            }
        }
        f32x4 cacc = {0.f, 0.f, 0.f, 0.f};
        #pragma unroll
        for (int kc = 0; kc < 4; ++kc)
            cacc = __builtin_amdgcn_mfma_f32_16x16x32_bf16(a[kc], bf[kc], cacc, 0, 0, 0);
        const float bb = bias[o];
        #pragma unroll
        for (int v = 0; v < 4; ++v) {
            const long rr = r0 + quad * 4 + v;
            if (rr < n) out[rr * C + o] = cacc[v] + cv[v] * bb;
        }
    }
}

extern "C" void kernel_launch(void* const* d_in, const int* in_sizes, int n_in,
                              void* d_out, int out_size, void* d_ws, size_t ws_size,
                              hipStream_t stream) {
    const float* x  = (const float*)d_in[0];
    const int*   ei = (const int*)d_in[1];
    const float* W  = (const float*)d_in[2];
    const float* b  = (const float*)d_in[3];
    float* out = (float*)d_out;

    const int n = in_sizes[0] / C;   // nodes
    const int e = in_sizes[1] / 2;   // edges (== n)
    const int* row = ei;
    const int* col = ei + e;

    int*   deg_i    = (int*)d_ws;            // [n]
    int*   cursor   = deg_i + n;             // [n]  (memset with deg)
    int*   offs     = cursor + n;            // [n]  (block-local exclusive scan)
    int*   csr_col  = offs + n;              // [e]
    float* csr_w    = (float*)(csr_col + e); // [e]
    float* dis      = csr_w + e;             // [n]
    float* nrm      = dis + n;               // [e]
    int*   partials = (int*)(nrm + e);       // [<=1024]

    const int nb = (n + 1023) / 1024;        // 489 for n=500k (must be <=1024)

    hipMemsetAsync(deg_i, 0, (size_t)2 * n * sizeof(int), stream);  // deg + cursor

    deg_kernel<<<(e + 255) / 256, 256, 0, stream>>>(row, deg_i, e);
    scan1_kernel<<<nb, 256, 0, stream>>>(deg_i, dis, offs, partials, n);
    scan2_kernel<<<1, 1024, 0, stream>>>(partials, nb);
    norm_kernel<<<(e + 255) / 256, 256, 0, stream>>>(row, col, dis, nrm, e);
    bucket_kernel<<<(e + 255) / 256, 256, 0, stream>>>(row, col, offs, partials, nrm,
                                                       cursor, csr_col, csr_w, e);

    int blocks = (n + 63) / 64;
    fused_kernel<<<blocks, 256, 0, stream>>>(
        (const f32x4*)x, csr_col, csr_w, offs, partials, deg_i,
        (const f32x4*)W, b, out, n);
}